// Round 2
// baseline (185.349 us; speedup 1.0000x reference)
//
#include <hip/hip_runtime.h>

// Nearest-neighbor gather resample.
// idx:    [B, 2, N] float32 (row, col) coords
// source: [B, 640, 640, 3] float32
// out:    [B, N, 3] float32; zero where rounded coord out of bounds.
//
// Semantics: coord = (int)(v + 0.5f)  (trunc toward zero) ==
// jnp.trunc(idx+0.5).astype(int32). Validity tested on UNCLAMPED coord.
//
// R1 changes vs R0:
//  - gather 12B pixel via one dwordx3 (aligned(4) struct) instead of 3x dword
//    -> 3x fewer divergent-gather L2 requests.
//  - XCD-aware block swizzle: blockIdx%8 == XCD; each XCD handles only
//    B/8 batches, one batch (4.9 MB ~= one L2) at a time -> L2 locality.

#define HS 640
#define WS 640
#define NC 3

struct alignas(4) F3 { float x, y, z; };

template <bool SWIZ>
__global__ __launch_bounds__(256) void resample_nn_kernel(
    const float* __restrict__ idx,   // [B, 2, N]
    const float* __restrict__ src,   // [B, HS, WS, NC]
    float* __restrict__ out,         // [B, N, NC]
    int N,                           // pixels per batch (quad-divisible)
    int blocks_per_batch,            // (N/4)/256
    int batches_per_xcd)             // B/8
{
    int b, q0;
    if (SWIZ) {
        // consecutive blockIdx -> consecutive XCDs (round-robin dispatch)
        int xcd  = blockIdx.x & 7;
        int slot = blockIdx.x >> 3;                  // per-XCD block sequence
        b  = xcd * batches_per_xcd + slot / blocks_per_batch;
        int blk = slot % blocks_per_batch;
        q0 = blk * (int)blockDim.x + (int)threadIdx.x;
    } else {
        long long tid = (long long)blockIdx.x * blockDim.x + threadIdx.x;
        int quads_per_b = N >> 2;
        b  = (int)(tid / quads_per_b);
        q0 = (int)(tid % quads_per_b);
    }
    int n0 = q0 << 2;

    const float* idx_b = idx + (size_t)b * 2 * N;
    float4 r4 = *(const float4*)(idx_b + n0);        // coalesced
    float4 c4 = *(const float4*)(idx_b + N + n0);    // coalesced

    const float* src_b = src + (size_t)b * (HS * WS * NC);

    float rr[4] = {r4.x, r4.y, r4.z, r4.w};
    float cc[4] = {c4.x, c4.y, c4.z, c4.w};

    float v[12];
#pragma unroll
    for (int i = 0; i < 4; ++i) {
        int ir = (int)(rr[i] + 0.5f);                // trunc toward zero
        int ic = (int)(cc[i] + 0.5f);
        bool valid = (ir >= 0) & (ic >= 0) & (ir < HS) & (ic < WS);
        int irc = min(max(ir, 0), HS - 1);
        int icc = min(max(ic, 0), WS - 1);
        // single 12B gather (dwordx3) -- clamped addr always in-bounds
        F3 px = *(const F3*)(src_b + ((size_t)irc * WS + icc) * NC);
        v[3 * i + 0] = valid ? px.x : 0.0f;
        v[3 * i + 1] = valid ? px.y : 0.0f;
        v[3 * i + 2] = valid ? px.z : 0.0f;
    }

    float4* o = (float4*)(out + ((size_t)b * N + n0) * NC);
    o[0] = make_float4(v[0], v[1], v[2], v[3]);
    o[1] = make_float4(v[4], v[5], v[6], v[7]);
    o[2] = make_float4(v[8], v[9], v[10], v[11]);
}

extern "C" void kernel_launch(void* const* d_in, const int* in_sizes, int n_in,
                              void* d_out, int out_size, void* d_ws, size_t ws_size,
                              hipStream_t stream) {
    const float* idx = (const float*)d_in[0];
    const float* src = (const float*)d_in[1];
    float* out = (float*)d_out;

    int B = in_sizes[1] / (HS * WS * NC);        // 16
    int N = in_sizes[0] / (2 * B);               // 262144

    int block = 256;
    int quads_per_b = N >> 2;

    if ((B % 8 == 0) && (quads_per_b % block == 0)) {
        int blocks_per_batch = quads_per_b / block;       // 256
        int batches_per_xcd  = B / 8;                     // 2
        int grid = B * blocks_per_batch;                  // 4096
        resample_nn_kernel<true><<<grid, block, 0, stream>>>(
            idx, src, out, N, blocks_per_batch, batches_per_xcd);
    } else {
        long long total_quads = (long long)B * quads_per_b;
        int grid = (int)((total_quads + block - 1) / block);
        resample_nn_kernel<false><<<grid, block, 0, stream>>>(
            idx, src, out, N, 0, 0);
    }
}